// Round 4
// baseline (371.394 us; speedup 1.0000x reference)
//
#include <hip/hip_runtime.h>
#include <cstdint>

constexpr int NV = 32000;   // vocab / N
constexpr int NE = 256;     // embed dim
constexpr int NH = 512;     // hidden / K (per split half)
constexpr int NB = 8;       // batch
constexpr int NS = 16;      // seq len
constexpr int NT = 20;      // time steps
constexpr int NSTEP = NS * NT;      // 320
constexpr int NM = NSTEP * NB;      // 2560 GEMM rows
constexpr int KD = 1024;            // split K (hi | lo)
constexpr float TH1 = 0.8f;
constexpr float TH2 = 1.0f;

typedef _Float16 f16x8 __attribute__((ext_vector_type(8)));
typedef _Float16 f16x4 __attribute__((ext_vector_type(4)));
typedef float f32x4 __attribute__((ext_vector_type(4)));

__device__ inline float clip01(float v) { return fminf(fmaxf(v, 0.f), 1.f); }

#define GL_LDS(gp, lp) \
  __builtin_amdgcn_global_load_lds((const __attribute__((address_space(1))) void*)(gp), \
                                   (__attribute__((address_space(3))) void*)(lp), 16, 0, 0)

__device__ inline void barsched() {
  __builtin_amdgcn_s_barrier();
  __builtin_amdgcn_sched_barrier(0);
}

// ---------------- K1: cur1[b][s][h] = embed[x[b,s],:] . W1[h,:] + b1[h] ----------------
__global__ void k_cur1(const int* __restrict__ x, const float* __restrict__ embed,
                       const float* __restrict__ W1, const float* __restrict__ b1,
                       float* __restrict__ cur1) {
  __shared__ float e[NE];
  int bs = blockIdx.x;                 // b*NS + s
  int row = x[bs];
  e[threadIdx.x] = embed[(size_t)row * NE + threadIdx.x];
  __syncthreads();
  for (int hh = 0; hh < 2; ++hh) {
    int h = threadIdx.x + hh * 256;
    const float* w = W1 + (size_t)h * NE;
    float acc = 0.f;
#pragma unroll 8
    for (int k = 0; k < NE; ++k) acc = fmaf(e[k], w[k], acc);
    cur1[(size_t)bs * NH + h] = acc + b1[h];
  }
}

// ---------------- K2: leaky recurrence -> packed/pre-swizzled spike tiles A2P ----------------
// A2P layout: 320 tiles of [128 rows][64 cols], tile g = (mt*16 + kk), col stored at
// (c&63) ^ ((row&7)*8). Tile image == exact LDS image for the GEMM stage loads.
__global__ void k_spk1(const float* __restrict__ cur1, const float* __restrict__ pbeta1,
                       _Float16* __restrict__ A2P, float* __restrict__ mem1_out) {
  int g = blockIdx.x * blockDim.x + threadIdx.x;   // 4096 = NB*NH
  int b = g >> 9, h = g & 511;
  float bc = clip01(pbeta1[0]);
  float mem = 0.f;
  const _Float16 one  = (_Float16)1.0f;
  const _Float16 sc   = (_Float16)4.8828125e-4f;   // 2^-11, exact in fp16
  const _Float16 zero = (_Float16)0.0f;
  const int kkh = h >> 6;            // hi k-block (0..7); lo block = kkh+8
  const int c63 = h & 63;
  for (int s = 0; s < NS; ++s) {
    float c = cur1[((size_t)b * NS + s) * NH + h];
    for (int t = 0; t < NT; ++t) {
      float rst = (mem > TH1) ? TH1 : 0.f;                       // reset1*TH1 (exact)
      mem = __fsub_rn(__fadd_rn(__fmul_rn(bc, mem), c), rst);    // ((b*m)+c)-r, np order
      bool spk = mem > TH1;
      int m = (s * NT + t) * NB + b;
      int mt = m >> 7, row = m & 127;
      int pos = c63 ^ ((row & 7) << 3);
      size_t base = ((size_t)mt * 16) * 8192 + row * 64 + pos;
      A2P[base + (size_t)kkh * 8192]       = spk ? one : zero;   // hi half
      A2P[base + (size_t)(kkh + 8) * 8192] = spk ? sc  : zero;   // lo half * 2^-11
    }
  }
  mem1_out[g] = mem;   // g == b*NH+h
}

// ---------------- Fused: W2-split + GEMM(128x128 tiles over m) + synaptic recurrence ----------------
// One block per 128-wide n-strip. 512 threads = 8 waves (2m x 4n), wave tile 64x32.
// Triple-buffered staging, prefetch depth 2 k-steps, ONE barrier per k-step.
__global__ __launch_bounds__(512, 1) void k_fused(
    const _Float16* __restrict__ A2P,  // packed spike tiles (320 x 16KB)
    const float* __restrict__ W2,      // [32000][512] fp32
    _Float16* __restrict__ B2P,        // packed per-block strips (250 x 16 tiles x 16KB)
    const float* __restrict__ b2,
    const float* __restrict__ pa2, const float* __restrict__ pb2,
    float* __restrict__ out) {
  __shared__ __attribute__((aligned(16))) _Float16 As[3 * 8192];   // 48 KB
  __shared__ __attribute__((aligned(16))) _Float16 Bs[3 * 8192];   // 48 KB
  __shared__ __attribute__((aligned(16))) float    Cl[128 * 128];  // 64 KB

  const int tid  = threadIdx.x;
  const int lane = tid & 63;
  const int wid  = tid >> 6;           // 0..7
  const int wm   = wid >> 2;           // 0..1 (m half)
  const int wn   = wid & 3;            // 0..3 (n quarter)
  const int n0   = blockIdx.x * 128;
  _Float16* strip = B2P + (size_t)blockIdx.x * (16 * 8192);

  // ---- phase 0: convert this block's W2 strip -> packed/pre-swizzled f16 tiles ----
  for (int it = 0; it < 32; ++it) {
    int idx = it * 512 + tid;          // 0..16383
    int v  = idx >> 7;                 // 0..127 (row)
    int c4 = (idx & 127) * 4;          // 0..508
    const float4 w4 = *(const float4*)&W2[(size_t)(n0 + v) * NH + c4];
    const float* wf = (const float*)&w4;
    f16x4 hv, lv;
#pragma unroll
    for (int i = 0; i < 4; ++i) {
      float w = wf[i];
      _Float16 h16 = (fabsf(w) < 6.103515625e-05f) ? (_Float16)0.f : (_Float16)w;
      hv[i] = h16;
      lv[i] = (_Float16)((w - (float)h16) * 2048.0f);   // exact residual * 2^11
    }
    int kk  = c4 >> 6;
    int pos = (c4 & 63) ^ ((v & 7) << 3);               // 4-aligned stays contiguous
    *(f16x4*)&strip[(size_t)kk * 8192 + v * 64 + pos]       = hv;
    *(f16x4*)&strip[(size_t)(kk + 8) * 8192 + v * 64 + pos] = lv;
  }
  asm volatile("s_waitcnt vmcnt(0)" ::: "memory");   // stores drained -> L2 visible
  barsched();

  // ---- recurrence state (registers) ----
  const float a2 = clip01(pa2[0]);
  const float bc = clip01(pb2[0]);
  const int vv = tid & 127;            // owned column
  const int bbase = tid >> 7;          // 0..3 ; owns b = bbase, bbase+4
  const float b2v = b2[n0 + vv];
  float syn[2] = {0.f, 0.f};
  float mem[2] = {0.f, 0.f};

  f32x4 acc[4][2] = {};

  // ---- staging: fully linear 1KB-per-wave chunks from packed tiles ----
  const _Float16* pA = A2P   + wid * 512 + lane * 8;   // per-lane src
  const _Float16* pB = strip + wid * 512 + lane * 8;
  _Float16* dA = As + wid * 512;                       // wave-uniform dest
  _Float16* dB = Bs + wid * 512;

  auto stage = [&](int buf, int g) {
    const _Float16* sA = pA + (size_t)g * 8192;
    const _Float16* sB = pB + (size_t)(g & 15) * 8192;
    GL_LDS(sA,        dA + buf * 8192);          // A rows 0..63
    GL_LDS(sA + 4096, dA + buf * 8192 + 4096);   // A rows 64..127
    GL_LDS(sB,        dB + buf * 8192);          // B rows 0..63
    GL_LDS(sB + 4096, dB + buf * 8192 + 4096);   // B rows 64..127
  };

  const int lr  = lane & 15;
  const int lk8 = (lane >> 4) * 8;
  const int sw  = (lr & 7) * 8;                        // read-side swizzle
  const int cr  = (lane >> 4) * 4, cc = lane & 15;

  stage(0, 0);
  stage(1, 1);
  for (int mt = 0; mt < 20; ++mt) {
    for (int t = 0; t < 16; ++t) {
      const int g = mt * 16 + t;
      const int buf = g % 3;
      if (g == 319) {
        asm volatile("s_waitcnt vmcnt(0)" ::: "memory");
      } else {
        asm volatile("s_waitcnt vmcnt(4)" ::: "memory");  // stage(g) complete
      }
      barsched();                                         // all waves: buf resident
      if (g <= 317) stage((g + 2) % 3, g + 2);            // after barrier: buf(g+2)==buf(g-1) safe
#pragma unroll
      for (int kf = 0; kf < 2; ++kf) {
        f16x8 af[4], bf[2];
        const int col = (kf * 32 + lk8) ^ sw;
#pragma unroll
        for (int mi = 0; mi < 4; ++mi)
          af[mi] = *(const f16x8*)&As[buf * 8192 + (wm * 64 + mi * 16 + lr) * 64 + col];
#pragma unroll
        for (int ni = 0; ni < 2; ++ni)
          bf[ni] = *(const f16x8*)&Bs[buf * 8192 + (wn * 32 + ni * 16 + lr) * 64 + col];
#pragma unroll
        for (int ni = 0; ni < 2; ++ni)
#pragma unroll
          for (int mi = 0; mi < 4; ++mi)
            acc[mi][ni] = __builtin_amdgcn_mfma_f32_16x16x32_f16(af[mi], bf[ni], acc[mi][ni], 0, 0, 0);
      }
    }
    // ---- epilogue: acc -> Cl, then 16 recurrence steps ----
    barsched();                                           // last k-step reads done everywhere
#pragma unroll
    for (int mi = 0; mi < 4; ++mi)
#pragma unroll
      for (int ni = 0; ni < 2; ++ni) {
#pragma unroll
        for (int j = 0; j < 4; ++j)
          Cl[(wm * 64 + mi * 16 + cr + j) * 128 + wn * 32 + ni * 16 + cc] = acc[mi][ni][j];
        acc[mi][ni] = (f32x4){0.f, 0.f, 0.f, 0.f};
      }
    barsched();                                           // Cl visible to all
    for (int st = 0; st < 16; ++st) {
      const int gs = mt * 16 + st;
#pragma unroll
      for (int p = 0; p < 2; ++p) {
        const int b = bbase + p * 4;
        float cur2 = __fadd_rn(Cl[(st * 8 + b) * 128 + vv], b2v);
        float rst = (mem[p] > TH2) ? 1.f : 0.f;            // reset from OLD mem2
        syn[p] = __fadd_rn(__fmul_rn(a2, syn[p]), cur2);
        mem[p] = __fsub_rn(__fadd_rn(__fmul_rn(bc, mem[p]), syn[p]), rst);
      }
      if (gs % 20 == 19) {                                 // last inner step of seq pos
        const int s = gs / 20;
#pragma unroll
        for (int p = 0; p < 2; ++p)
          out[((size_t)(bbase + p * 4) * NS + s) * NV + n0 + vv] = (mem[p] > TH2) ? 1.f : 0.f;
      }
    }
    barsched();                                           // Cl reads done before next epilogue write
  }
  // ---- final states ----
#pragma unroll
  for (int p = 0; p < 2; ++p) {
    out[(size_t)4100096 + (size_t)(bbase + p * 4) * NV + n0 + vv] = syn[p];  // syn2
    out[(size_t)4356096 + (size_t)(bbase + p * 4) * NV + n0 + vv] = mem[p];  // mem2
  }
}

extern "C" void kernel_launch(void* const* d_in, const int* in_sizes, int n_in,
                              void* d_out, int out_size, void* d_ws, size_t ws_size,
                              hipStream_t stream) {
  const int*   x     = (const int*)d_in[0];
  const float* embed = (const float*)d_in[1];
  const float* W1    = (const float*)d_in[2];
  const float* b1    = (const float*)d_in[3];
  const float* W2    = (const float*)d_in[4];
  const float* b2    = (const float*)d_in[5];
  const float* pb1   = (const float*)d_in[6];
  const float* pa2   = (const float*)d_in[7];
  const float* pb2   = (const float*)d_in[8];
  float* out = (float*)d_out;

  char* ws = (char*)d_ws;
  float* cur1 = (float*)ws;                                  // 262144 B
  _Float16* A2P = (_Float16*)(ws + 262144);                  // 320*16KB = 5242880 B
  _Float16* B2P = (_Float16*)(ws + 262144 + (size_t)320 * 8192 * 2);  // 250*256KB = 65.5 MB

  hipLaunchKernelGGL(k_cur1, dim3(NB * NS), dim3(256), 0, stream, x, embed, W1, b1, cur1);
  hipLaunchKernelGGL(k_spk1, dim3(16), dim3(256), 0, stream, cur1, pb1, A2P, out + 4096000);
  hipLaunchKernelGGL(k_fused, dim3(NV / 128), dim3(512), 0, stream,
                     A2P, W2, B2P, b2, pa2, pb2, out);
}

// Round 5
// 297.785 us; speedup vs baseline: 1.2472x; 1.2472x over previous
//
#include <hip/hip_runtime.h>
#include <cstdint>

constexpr int NV = 32000;   // vocab / N
constexpr int NE = 256;     // embed dim
constexpr int NH = 512;     // hidden / K
constexpr int NB = 8;       // batch
constexpr int NS = 16;      // seq len
constexpr int NT = 20;      // time steps
constexpr float TH1 = 0.8f;
constexpr float TH2 = 1.0f;

typedef _Float16 f16x8 __attribute__((ext_vector_type(8)));
typedef float f32x4 __attribute__((ext_vector_type(4)));

__device__ inline float clip01(float v) { return fminf(fmaxf(v, 0.f), 1.f); }

#define GL_LDS(gp, lp) \
  __builtin_amdgcn_global_load_lds((const __attribute__((address_space(1))) void*)(gp), \
                                   (__attribute__((address_space(3))) void*)(lp), 16, 0, 0)

__device__ inline void barsched() {
  __builtin_amdgcn_s_barrier();
  __builtin_amdgcn_sched_barrier(0);
}

// ---------------- K1: cur1[b][s][h] = embed[x[b,s],:] . W1[h,:] + b1[h] ----------------
__global__ void k_cur1(const int* __restrict__ x, const float* __restrict__ embed,
                       const float* __restrict__ W1, const float* __restrict__ b1,
                       float* __restrict__ cur1) {
  __shared__ float e[NE];
  int bs = blockIdx.x;
  int row = x[bs];
  e[threadIdx.x] = embed[(size_t)row * NE + threadIdx.x];
  __syncthreads();
  for (int hh = 0; hh < 2; ++hh) {
    int h = threadIdx.x + hh * 256;
    const float* w = W1 + (size_t)h * NE;
    float acc = 0.f;
#pragma unroll 8
    for (int k = 0; k < NE; ++k) acc = fmaf(e[k], w[k], acc);
    cur1[(size_t)bs * NH + h] = acc + b1[h];
  }
}

// ---------------- K2: leaky recurrence -> packed spike tiles (K=512, spikes only) ---------
// A2P = 320 tiles of [64 rows][64 cols] f16 (8KB), tile u = (m>>6)*8 + (h>>6),
// elem (row=m&63, col=h&63) stored at row*64 + (col ^ ((row&7)*8)).  row&7 == b.
__global__ void k_spk1(const float* __restrict__ cur1, const float* __restrict__ pbeta1,
                       _Float16* __restrict__ A2P, float* __restrict__ mem1_out) {
  int g = blockIdx.x * blockDim.x + threadIdx.x;   // 4096 = NB*NH
  int b = g >> 9, h = g & 511;
  float bc = clip01(pbeta1[0]);
  float mem = 0.f;
  const _Float16 one  = (_Float16)1.0f;
  const _Float16 zero = (_Float16)0.0f;
  const int ks  = h >> 6;
  const int col = (h & 63) ^ (b << 3);
  for (int s = 0; s < NS; ++s) {
    float c = cur1[((size_t)b * NS + s) * NH + h];
    for (int t = 0; t < NT; ++t) {
      float rst = (mem > TH1) ? TH1 : 0.f;
      mem = __fsub_rn(__fadd_rn(__fmul_rn(bc, mem), c), rst);    // np order
      bool spk = mem > TH1;
      int gs = s * NT + t;
      size_t addr = ((size_t)((gs >> 3) * 8 + ks)) * 4096 + ((gs & 7) * 8 + b) * 64 + col;
      A2P[addr] = spk ? one : zero;
    }
  }
  mem1_out[g] = mem;
}

// ---------------- Fused: B-in-registers GEMM + synaptic recurrence ----------------
// Block = 256 thr = 4 waves (2m x 2n), n-strip of 64 cols, 2 strips per block.
// B (W2 strip, f16 hi/lo split, K=512) lives in VGPRs: 256 regs/wave.
// A (spikes) streamed tile-by-tile via global_load_lds into an 8-buffer LDS ring.
__global__ __launch_bounds__(256, 1) void k_fused(
    const _Float16* __restrict__ A2P,  // 320 x 8KB packed spike tiles
    const float* __restrict__ W2,      // [32000][512] fp32
    const float* __restrict__ b2,
    const float* __restrict__ pa2, const float* __restrict__ pb2,
    float* __restrict__ out) {
  __shared__ __attribute__((aligned(16))) _Float16 As[8 * 4096];   // 64 KB ring
  __shared__ __attribute__((aligned(16))) float    Cl[64 * 68];    // 17.4 KB (pad 68)

  const int tid  = threadIdx.x;
  const int lane = tid & 63;
  const int wid  = tid >> 6;           // 0..3
  const int wm   = wid >> 1;           // m half (0..1)
  const int wn   = wid & 1;            // n half (0..1)

  const int lr  = lane & 15;
  const int lk8 = (lane >> 4) * 8;
  const int sw  = (lr & 7) * 8;        // read-side swizzle
  const int cr  = (lane >> 4) * 4, cc = lane & 15;

  const float a2  = clip01(pa2[0]);
  const float bcl = clip01(pb2[0]);
  const int vv = tid & 63;             // owned column within strip
  const int bb = tid >> 6;             // owns b = bb, bb+4

  // staging pointers (per-lane src includes lane*16B; dest wave-uniform)
  const _Float16* pA = A2P + wid * 1024 + lane * 8;
  _Float16* dA = As + wid * 1024;

  for (int rep = 0; rep < 2; ++rep) {
    const int strip = blockIdx.x * 2 + rep;
    const int n0 = strip * 64;

    // ---- B-frag load + hi/lo f16 split (registers; K=512) ----
    f16x8 bh[2][16], bl[2][16];
#pragma unroll
    for (int ni = 0; ni < 2; ++ni) {
#pragma unroll
      for (int kb = 0; kb < 16; ++kb) {
        const int n  = n0 + wn * 32 + ni * 16 + lr;
        const int k0 = kb * 32 + lk8;
        const float* wp = W2 + (size_t)n * NH + k0;
        const float4 wa = *(const float4*)wp;
        const float4 wb = *(const float4*)(wp + 4);
        const float wf[8] = {wa.x, wa.y, wa.z, wa.w, wb.x, wb.y, wb.z, wb.w};
        f16x8 hv, lv;
#pragma unroll
        for (int i = 0; i < 8; ++i) {
          float w = wf[i];
          _Float16 h16 = (fabsf(w) < 6.103515625e-05f) ? (_Float16)0.f : (_Float16)w;
          hv[i] = h16;
          lv[i] = (_Float16)((w - (float)h16) * 2048.0f);   // exact residual * 2^11
        }
        bh[ni][kb] = hv;
        bl[ni][kb] = lv;
      }
    }
    const float b2v = b2[n0 + vv];
    float syn[2] = {0.f, 0.f};
    float mem[2] = {0.f, 0.f};
    f32x4 ah[2][2] = {};
    f32x4 al[2][2] = {};

    asm volatile("s_waitcnt vmcnt(0)" ::: "memory");   // clean counter for manual discipline
    __syncthreads();

    auto stage = [&](int u) {                          // stage tile u into ring buf u&7
      const _Float16* s = pA + (size_t)u * 4096;
      _Float16* d = dA + (u & 7) * 4096;
      GL_LDS(s, d);
      GL_LDS(s + 512, d + 512);
    };

    stage(0); stage(1); stage(2);

    for (int mt = 0; mt < 40; ++mt) {
      const int mt8 = mt * 8;
#pragma unroll
      for (int ks = 0; ks < 8; ++ks) {
        const int u = mt8 + ks;
        const int buf = u & 7;
        if (u < 317) {
          stage(u + 3);
          asm volatile("s_waitcnt vmcnt(6)" ::: "memory");   // stage(u) complete
        } else {                                             // tail: mt=39, ks=5..7
          if (ks == 5)      asm volatile("s_waitcnt vmcnt(4)" ::: "memory");
          else if (ks == 6) asm volatile("s_waitcnt vmcnt(2)" ::: "memory");
          else              asm volatile("s_waitcnt vmcnt(0)" ::: "memory");
        }
        barsched();
#pragma unroll
        for (int kf = 0; kf < 2; ++kf) {
          const int kb = ks * 2 + kf;                        // compile-time after unroll
          const int col = (kf * 32 + lk8) ^ sw;
          const f16x8 a0 = *(const f16x8*)&As[buf * 4096 + (wm * 32 + lr) * 64 + col];
          const f16x8 a1 = *(const f16x8*)&As[buf * 4096 + (wm * 32 + 16 + lr) * 64 + col];
          ah[0][0] = __builtin_amdgcn_mfma_f32_16x16x32_f16(a0, bh[0][kb], ah[0][0], 0, 0, 0);
          ah[1][0] = __builtin_amdgcn_mfma_f32_16x16x32_f16(a1, bh[0][kb], ah[1][0], 0, 0, 0);
          ah[0][1] = __builtin_amdgcn_mfma_f32_16x16x32_f16(a0, bh[1][kb], ah[0][1], 0, 0, 0);
          ah[1][1] = __builtin_amdgcn_mfma_f32_16x16x32_f16(a1, bh[1][kb], ah[1][1], 0, 0, 0);
          al[0][0] = __builtin_amdgcn_mfma_f32_16x16x32_f16(a0, bl[0][kb], al[0][0], 0, 0, 0);
          al[1][0] = __builtin_amdgcn_mfma_f32_16x16x32_f16(a1, bl[0][kb], al[1][0], 0, 0, 0);
          al[0][1] = __builtin_amdgcn_mfma_f32_16x16x32_f16(a0, bl[1][kb], al[0][1], 0, 0, 0);
          al[1][1] = __builtin_amdgcn_mfma_f32_16x16x32_f16(a1, bl[1][kb], al[1][1], 0, 0, 0);
        }
      }
      // ---- epilogue: combine hi/lo, park in Cl, run 8 recurrence steps ----
      barsched();                                       // all MFMA reads of this mt done
#pragma unroll
      for (int mi = 0; mi < 2; ++mi)
#pragma unroll
        for (int ni = 0; ni < 2; ++ni) {
#pragma unroll
          for (int j = 0; j < 4; ++j)
            Cl[(wm * 32 + mi * 16 + cr + j) * 68 + wn * 32 + ni * 16 + cc] =
                fmaf(al[mi][ni][j], 4.8828125e-4f, ah[mi][ni][j]);
          ah[mi][ni] = (f32x4){0.f, 0.f, 0.f, 0.f};
          al[mi][ni] = (f32x4){0.f, 0.f, 0.f, 0.f};
        }
      __syncthreads();                                  // Cl visible
#pragma unroll
      for (int st = 0; st < 8; ++st) {
        const int gs = mt8 + st;
#pragma unroll
        for (int p = 0; p < 2; ++p) {
          const int b = bb + p * 4;
          float cur2 = __fadd_rn(Cl[(st * 8 + b) * 68 + vv], b2v);
          float rst = (mem[p] > TH2) ? 1.f : 0.f;        // reset from OLD mem2
          syn[p] = __fadd_rn(__fmul_rn(a2, syn[p]), cur2);
          mem[p] = __fsub_rn(__fadd_rn(__fmul_rn(bcl, mem[p]), syn[p]), rst);
        }
        if (gs % 20 == 19) {                             // last inner step of seq pos
          const int s = gs / 20;
#pragma unroll
          for (int p = 0; p < 2; ++p)
            out[((size_t)(bb + p * 4) * NS + s) * NV + n0 + vv] = (mem[p] > TH2) ? 1.f : 0.f;
        }
      }
      __syncthreads();                                  // Cl reads done before next mt
    }
    // ---- final states for this strip ----
#pragma unroll
    for (int p = 0; p < 2; ++p) {
      out[(size_t)4100096 + (size_t)(bb + p * 4) * NV + n0 + vv] = syn[p];  // syn2
      out[(size_t)4356096 + (size_t)(bb + p * 4) * NV + n0 + vv] = mem[p];  // mem2
    }
  }
}

extern "C" void kernel_launch(void* const* d_in, const int* in_sizes, int n_in,
                              void* d_out, int out_size, void* d_ws, size_t ws_size,
                              hipStream_t stream) {
  const int*   x     = (const int*)d_in[0];
  const float* embed = (const float*)d_in[1];
  const float* W1    = (const float*)d_in[2];
  const float* b1    = (const float*)d_in[3];
  const float* W2    = (const float*)d_in[4];
  const float* b2    = (const float*)d_in[5];
  const float* pb1   = (const float*)d_in[6];
  const float* pa2   = (const float*)d_in[7];
  const float* pb2   = (const float*)d_in[8];
  float* out = (float*)d_out;

  char* ws = (char*)d_ws;
  float* cur1 = (float*)ws;                            // 262144 B
  _Float16* A2P = (_Float16*)(ws + 262144);            // 320 tiles x 8KB = 2.62 MB

  hipLaunchKernelGGL(k_cur1, dim3(NB * NS), dim3(256), 0, stream, x, embed, W1, b1, cur1);
  hipLaunchKernelGGL(k_spk1, dim3(16), dim3(256), 0, stream, cur1, pb1, A2P, out + 4096000);
  hipLaunchKernelGGL(k_fused, dim3(250), dim3(256), 0, stream,
                     A2P, W2, b2, pa2, pb2, out);
}